// Round 13
// baseline (62.044 us; speedup 1.0000x reference)
//
#include <hip/hip_runtime.h>
#include <hip/hip_bf16.h>
#include <cstdint>

#define NROWS 8192
#define NPER  4096
#define DIM   512
#define TEMP_INV 10.0f
#define FP8_SCALE 16.0f          // z scaled by 16 before e4m3 quantization
#define DOT_UNSCALE (1.0f / 256.0f)  // undo FP8_SCALE^2 on dot products
#define NB    64        // 8192 / 128 row-blocks
#define NBLK  2080      // NB*(NB+1)/2 upper-tri 128x128 tiles
#define PAIR_OFF 32     // NPER / 128

typedef float f32x4 __attribute__((ext_vector_type(4)));
typedef long  lx2   __attribute__((ext_vector_type(2)));   // 16 B = 2 fp8 frags

// ---------------------------------------------------------------------------
// Kernel 1: L2-normalize rows of [view0; view1] -> z (fp8 e4m3, [8192][512]),
// scaled by FP8_SCALE. Also zeroes rowsum and out.
// ---------------------------------------------------------------------------
__global__ __launch_bounds__(256) void k_normalize(const float* __restrict__ v0,
                                                   const float* __restrict__ v1,
                                                   unsigned char* __restrict__ z,
                                                   float* __restrict__ rowsum,
                                                   float* __restrict__ out) {
  if (blockIdx.x < 32) rowsum[blockIdx.x * 256 + threadIdx.x] = 0.f;
  if (blockIdx.x == 0 && threadIdx.x == 0) out[0] = 0.f;
  const int wid  = (blockIdx.x * 256 + threadIdx.x) >> 6;  // row
  const int lane = threadIdx.x & 63;
  if (wid >= NROWS) return;
  const float* src = (wid < NPER) ? (v0 + (size_t)wid * DIM)
                                  : (v1 + (size_t)(wid - NPER) * DIM);
  float4 a = *(const float4*)(src + lane * 8);
  float4 b = *(const float4*)(src + lane * 8 + 4);
  float ss = a.x*a.x + a.y*a.y + a.z*a.z + a.w*a.w
           + b.x*b.x + b.y*b.y + b.z*b.z + b.w*b.w;
  #pragma unroll
  for (int m = 1; m < 64; m <<= 1) ss += __shfl_xor(ss, m);
  float inv = FP8_SCALE / fmaxf(sqrtf(ss), 1e-12f);
  int w0 = __builtin_amdgcn_cvt_pk_fp8_f32(a.x * inv, a.y * inv, 0, false);
  w0     = __builtin_amdgcn_cvt_pk_fp8_f32(a.z * inv, a.w * inv, w0, true);
  int w1 = __builtin_amdgcn_cvt_pk_fp8_f32(b.x * inv, b.y * inv, 0, false);
  w1     = __builtin_amdgcn_cvt_pk_fp8_f32(b.z * inv, b.w * inv, w1, true);
  uint2 p; p.x = (unsigned)w0; p.y = (unsigned)w1;
  *(uint2*)(z + (size_t)wid * DIM + lane * 8) = p;
}

// ---------------------------------------------------------------------------
// Kernel 2: symmetric fused G = z z^T in FP8 e4m3. 128x128 upper-tri tiles,
// 4 waves (2x2), per-wave 64x64 (acc[4][4] = 64 AGPR), 3 blocks/CU.
// R13 hybrid: A double-buffered in LDS (2 x 16 KB = 32 KB) with counted
// vmcnt(4) certify (A(kt) staged at end of iter kt-2 -> ~1-iter lead);
// B read DIRECT from global (L2-resident z) into registers, wave-local,
// no barrier involvement. Removes the block-wide 32 KB drain per iter --
// the cost R4-R12 counters showed was never hidden.
// k-relabeling: logical 16B-slot s = g + 4*p (A and B identically ->
// dot unchanged). B wave-load (fixed n,p): 16 rows x 64 contiguous B =
// 16 full lines (perfect coalescing). A LDS read at phys slot
// (g+4p)^(r0&7): every consecutive-8-lane group covers all 8 slots
// exactly once -> conflict-free (same family as R4/R10, measured 0).
// vmcnt ledger (per wave, in-order issue; gload_lds counted by compiler):
//   top iter kt: outstanding <= {A(kt),A(kt+1)} -> vmcnt(4) certifies A(kt)
//   (vmcnt(0) at kt=3); B(kt) issued after barrier, consumed same iter via
//   compiler waits; stage A(kt+2) only after the read-drain barrier.
// R8 super-tile locality map, rule #21 staging pre-swizzle kept.
// Positive-pair dots harvested from tiles with bj-bi == 32.
// ---------------------------------------------------------------------------
__global__ __launch_bounds__(256, 3) void k_gemm_sym(const unsigned char* __restrict__ z,
                                                     float* __restrict__ rowsum,
                                                     float* __restrict__ s) {
  __shared__ __align__(16) unsigned char As[2][128 * 128]; // 2 x 16 KB

  const int tid  = threadIdx.x;
  const int lane = tid & 63;
  const int w    = tid >> 6;      // 0..3
  const int wr   = w >> 1;        // 0..1 (row half)
  const int wc   = w & 1;         // 0..1 (col half)

  // T1 chunking: XCD x processes enumeration indices [x*260, (x+1)*260).
  const int orig = blockIdx.x;
  const int t = (orig & 7) * (NBLK / 8) + (orig >> 3);

  // ---- super-tile decode (R8) ----
  int a = 0;
  while (a < 7 && 484 * (a + 1) - 32 * (a + 1) * a <= t) ++a;
  int l = t - (484 * a - 32 * a * (a - 1));
  int ri, rj, sj;
  if (l < 36) {                      // diagonal super (si == sj == a)
    sj = a;
    ri = 0;
    while (l >= 8 - ri) { l -= 8 - ri; ++ri; }
    rj = ri + l;
  } else {                           // off-diagonal supers, 64 tiles each
    l -= 36;
    sj = a + 1 + (l >> 6);
    const int ll = l & 63;
    ri = ll >> 3; rj = ll & 7;
  }
  const int bi = a * 8 + ri;
  const int bj = sj * 8 + rj;
  const int brow = bi * 128;
  const int bcol = bj * 128;
  const bool diag = (bi == bj);
  const bool pair = (bj - bi == PAIR_OFF);  // contains positive-pair diagonal

  f32x4 acc[4][4];
  const f32x4 zero = {0.f, 0.f, 0.f, 0.f};
  #pragma unroll
  for (int m = 0; m < 4; ++m)
    #pragma unroll
    for (int n = 0; n < 4; ++n) acc[m][n] = zero;

  // stage one BK=128 A-slab (16 KB) into buffer buf. 4 gload_lds/thread.
  // Chunk = 8 rows x 128 B. LDS dest linear; global source pre-swizzled
  // (rule #21): 16B-slot ^= (row & 7).
  const int srow = (lane >> 3);                  // 0..7 row within chunk
  const int skof = 16 * ((lane & 7) ^ srow);     // pre-swizzled k-offset (bytes)
  auto stageA = [&](int buf, int k0) {
    #pragma unroll
    for (int i = 0; i < 4; ++i) {
      const int c = w * 4 + i;                   // chunk 0..15 (8 rows each)
      const int row_in = c * 8 + srow;
      const unsigned char* ga = z + (size_t)(brow + row_in) * DIM + k0 + skof;
      __builtin_amdgcn_global_load_lds(
          (const __attribute__((address_space(1))) void*)ga,
          (__attribute__((address_space(3))) void*)(&As[buf][c * 1024]), 16, 0, 0);
    }
  };

  const int r0 = lane & 15;
  const int g  = lane >> 4;
  // B base for this wave: rows bcol + wc*64 + n*16 + r0; per (n,p) the lane
  // reads 16 B at byte k0 + g*16 + p*64 (logical slot g+4p).
  const unsigned char* zB = z + (size_t)(bcol + wc * 64 + r0) * DIM + g * 16;

  // prologue: A0 -> buf0, A1 -> buf1 (8 loads/thread in flight)
  stageA(0, 0);
  stageA(1, 128);

  #pragma unroll
  for (int kt = 0; kt < 4; ++kt) {
    const int cur = kt & 1;
    const int k0 = kt * 128;
    // certify A(kt): outstanding <= {A(kt), A(kt+1)}; keep 4 newest in flight
    if (kt < 3) asm volatile("s_waitcnt vmcnt(4)" ::: "memory");
    else        asm volatile("s_waitcnt vmcnt(0)" ::: "memory");
    __builtin_amdgcn_s_barrier();

    // B(kt): 8 x 16-B wave-local register loads (L2-hit; compiler-managed
    // waits). Issued before the A ds_reads so latency hides under them.
    lx2 bq[4][2];
    #pragma unroll
    for (int n = 0; n < 4; ++n)
      #pragma unroll
      for (int p = 0; p < 2; ++p)
        bq[n][p] = *(const lx2*)(zB + (size_t)(n * 16) * DIM + k0 + p * 64);
    __builtin_amdgcn_sched_barrier(0);           // pin issue point

    const char* Ab = (const char*)&As[cur][0] + (size_t)(wr * 64 + r0) * 128;
    #pragma unroll
    for (int p = 0; p < 2; ++p) {
      lx2 aq[4];
      #pragma unroll
      for (int m = 0; m < 4; ++m)
        aq[m] = *(const lx2*)(Ab + m * (16 * 128) + (((g + 4 * p) ^ (r0 & 7)) << 4));
      #pragma unroll
      for (int m = 0; m < 4; ++m)
        #pragma unroll
        for (int n = 0; n < 4; ++n) {
          acc[m][n] = __builtin_amdgcn_mfma_f32_16x16x32_fp8_fp8(
              aq[m][0], bq[n][p][0], acc[m][n], 0, 0, 0);
          acc[m][n] = __builtin_amdgcn_mfma_f32_16x16x32_fp8_fp8(
              aq[m][1], bq[n][p][1], acc[m][n], 0, 0, 0);
        }
    }
    // all reads of buf cur done in this wave; sync all waves; then cur is
    // free to be overwritten by A(kt+2).
    asm volatile("s_waitcnt lgkmcnt(0)" ::: "memory");
    __builtin_amdgcn_sched_barrier(0);
    __builtin_amdgcn_s_barrier();
    if (kt < 2) stageA(cur, (kt + 2) * 128);
  }

  // ---- epilogue: unscale; exp(10*g); row + col sums; pair dots ----
  // smem reduction arrays aliased into As[0] (last A read was buf1 = As[1];
  // all waves past the final barrier).
  float (*racc)[128] = (float (*)[128])As;        // [2][128]
  float (*cacc)[128] = ((float (*)[128])As) + 2;  // [2][128]

  float cs[4] = {0.f, 0.f, 0.f, 0.f};
  const int grow0 = brow + wr * 64;
  const int gcol0 = bcol + wc * 64;
  const float expc = TEMP_INV * DOT_UNSCALE;
  #pragma unroll
  for (int m = 0; m < 4; ++m) {
    #pragma unroll
    for (int j = 0; j < 4; ++j) {
      const int grow = grow0 + m * 16 + g * 4 + j;
      float v = 0.f;
      #pragma unroll
      for (int n = 0; n < 4; ++n) {
        const int gcol = gcol0 + n * 16 + r0;
        const float rawacc = acc[m][n][j];
        const float e = __expf(rawacc * expc);
        if (grow != gcol) { v += e; cs[n] += e; }   // skip self-similarity
        if (pair && (grow + NPER == gcol)) {        // positive-pair raw dot
          const float raw = rawacc * DOT_UNSCALE;
          s[grow] = raw;                            // dot(z_i, z_{i+NPER})
          s[gcol] = raw;                            // symmetric partner
        }
      }
      v += __shfl_xor(v, 1);
      v += __shfl_xor(v, 2);
      v += __shfl_xor(v, 4);
      v += __shfl_xor(v, 8);
      if (r0 == 0) racc[wc][wr * 64 + m * 16 + g * 4 + j] = v;
    }
  }
  #pragma unroll
  for (int n = 0; n < 4; ++n) {
    float v = cs[n];
    v += __shfl_xor(v, 16);
    v += __shfl_xor(v, 32);
    if (lane < 16) cacc[wr][wc * 64 + n * 16 + lane] = v;
  }
  __syncthreads();
  if (tid < 128) {
    atomicAdd(&rowsum[brow + tid], racc[0][tid] + racc[1][tid]);
  } else if (!diag) {
    const int i = tid - 128;
    atomicAdd(&rowsum[bcol + i], cacc[0][i] + cacc[1][i]);
  }
}

// ---------------------------------------------------------------------------
// Kernel 3: loss = mean_i( log(denom_i) - s_i/T ), 32 blocks + atomicAdd.
// ---------------------------------------------------------------------------
__global__ __launch_bounds__(256) void k_loss(const float* __restrict__ rowsum,
                                              const float* __restrict__ s,
                                              float* __restrict__ out) {
  __shared__ float red[4];
  const int i = blockIdx.x * 256 + threadIdx.x;
  float v = logf(rowsum[i]) - s[i] * TEMP_INV;
  #pragma unroll
  for (int m = 1; m < 64; m <<= 1) v += __shfl_xor(v, m);
  const int w = threadIdx.x >> 6;
  if ((threadIdx.x & 63) == 0) red[w] = v;
  __syncthreads();
  if (threadIdx.x == 0)
    atomicAdd(out, (red[0] + red[1] + red[2] + red[3]) * (1.0f / (float)NROWS));
}

extern "C" void kernel_launch(void* const* d_in, const int* in_sizes, int n_in,
                              void* d_out, int out_size, void* d_ws, size_t ws_size,
                              hipStream_t stream) {
  const float* v0 = (const float*)d_in[0];
  const float* v1 = (const float*)d_in[1];
  float* out = (float*)d_out;

  unsigned char* z = (unsigned char*)d_ws;                      // 8192*512 B
  float* rowsum = (float*)((char*)d_ws + (size_t)NROWS * DIM);
  float* s      = rowsum + NROWS;

  k_normalize<<<NROWS / 4, 256, 0, stream>>>(v0, v1, z, rowsum, out);
  k_gemm_sym<<<NBLK, 256, 0, stream>>>(z, rowsum, s);
  k_loss<<<NROWS / 256, 256, 0, stream>>>(rowsum, s, out);
}

// Round 14
// 49.749 us; speedup vs baseline: 1.2472x; 1.2472x over previous
//
#include <hip/hip_runtime.h>
#include <hip/hip_bf16.h>
#include <cstdint>

#define NROWS 8192
#define NPER  4096
#define DIM   512
#define ZPITCH 576      // z row stride in BYTES: 512 data + 64 pad (9 x 64 B)
                        // breaks the power-of-two L2 channel-hash alias that
                        // capped 512-B-stride staging at 10.8 B/cyc/CU (R10)
                        // vs 17.3 for 1024-B-stride bf16 (R4) -- same pattern.
#define TEMP_INV 10.0f
#define FP8_SCALE 16.0f          // z scaled by 16 before e4m3 quantization
#define DOT_UNSCALE (1.0f / 256.0f)  // undo FP8_SCALE^2 on dot products
#define NB    64        // 8192 / 128 row-blocks
#define NBLK  2080      // NB*(NB+1)/2 upper-tri 128x128 tiles
#define PAIR_OFF 32     // NPER / 128

typedef float f32x4 __attribute__((ext_vector_type(4)));
typedef long  lx2   __attribute__((ext_vector_type(2)));   // 16 B = 2 fp8 frags

// ---------------------------------------------------------------------------
// Kernel 1: L2-normalize rows of [view0; view1] -> z (fp8 e4m3,
// [8192] rows x 512 B data at 576-B pitch), scaled by FP8_SCALE.
// Also zeroes rowsum and out.
// ---------------------------------------------------------------------------
__global__ __launch_bounds__(256) void k_normalize(const float* __restrict__ v0,
                                                   const float* __restrict__ v1,
                                                   unsigned char* __restrict__ z,
                                                   float* __restrict__ rowsum,
                                                   float* __restrict__ out) {
  if (blockIdx.x < 32) rowsum[blockIdx.x * 256 + threadIdx.x] = 0.f;
  if (blockIdx.x == 0 && threadIdx.x == 0) out[0] = 0.f;
  const int wid  = (blockIdx.x * 256 + threadIdx.x) >> 6;  // row
  const int lane = threadIdx.x & 63;
  if (wid >= NROWS) return;
  const float* src = (wid < NPER) ? (v0 + (size_t)wid * DIM)
                                  : (v1 + (size_t)(wid - NPER) * DIM);
  float4 a = *(const float4*)(src + lane * 8);
  float4 b = *(const float4*)(src + lane * 8 + 4);
  float ss = a.x*a.x + a.y*a.y + a.z*a.z + a.w*a.w
           + b.x*b.x + b.y*b.y + b.z*b.z + b.w*b.w;
  #pragma unroll
  for (int m = 1; m < 64; m <<= 1) ss += __shfl_xor(ss, m);
  float inv = FP8_SCALE / fmaxf(sqrtf(ss), 1e-12f);
  // pack 8 fp8 e4m3 (hardware v_cvt_pk_fp8_f32, RNE, OCP format on gfx950)
  int w0 = __builtin_amdgcn_cvt_pk_fp8_f32(a.x * inv, a.y * inv, 0, false);
  w0     = __builtin_amdgcn_cvt_pk_fp8_f32(a.z * inv, a.w * inv, w0, true);
  int w1 = __builtin_amdgcn_cvt_pk_fp8_f32(b.x * inv, b.y * inv, 0, false);
  w1     = __builtin_amdgcn_cvt_pk_fp8_f32(b.z * inv, b.w * inv, w1, true);
  uint2 p; p.x = (unsigned)w0; p.y = (unsigned)w1;
  *(uint2*)(z + (size_t)wid * ZPITCH + lane * 8) = p;
}

// ---------------------------------------------------------------------------
// Kernel 2: symmetric fused G = z z^T in FP8 e4m3 (mfma_f32_16x16x32_fp8_fp8).
// This is the R10-verified kernel (best measured: GEMM ~40.3 us, 0 bank
// conflicts) with ONE change: z is read at 576-B row pitch (R14).
// 128x128 upper-tri tiles, 4 waves (2x2), per-wave 64x64 (acc[4][4] =
// 64 AGPR), BK=128 SINGLE-buffered (32 KB LDS, 3 blocks/CU residency
// ceiling -- R5/R12 proved 4 is never granted), 4 K-iterations.
// Conflict-free LDS reads: 16 B per lane (ds_read_b128) at phys 16B-slot
// (2g+p)^(r0&7), row stride 128 B -- the R4/R10-verified 0-conflict pattern.
// Each b128 holds TWO 8-B MFMA fragments; k-regrouping applied identically
// to A and B so the dot product is unchanged.
// Staging pre-swizzles the global source (rule #21). R8 super-tile locality
// map kept. Positive-pair dots harvested from tiles with bj-bi == 32.
// ---------------------------------------------------------------------------
__global__ __launch_bounds__(256, 3) void k_gemm_sym(const unsigned char* __restrict__ z,
                                                     float* __restrict__ rowsum,
                                                     float* __restrict__ s) {
  __shared__ __align__(16) unsigned char As[128 * 128];   // 16 KB
  __shared__ __align__(16) unsigned char Bs[128 * 128];   // 16 KB

  const int tid  = threadIdx.x;
  const int lane = tid & 63;
  const int w    = tid >> 6;      // 0..3
  const int wr   = w >> 1;        // 0..1 (row half)
  const int wc   = w & 1;         // 0..1 (col half)

  // T1 chunking: XCD x processes enumeration indices [x*260, (x+1)*260).
  const int orig = blockIdx.x;
  const int t = (orig & 7) * (NBLK / 8) + (orig >> 3);

  // ---- super-tile decode (R8) ----
  int a = 0;
  while (a < 7 && 484 * (a + 1) - 32 * (a + 1) * a <= t) ++a;
  int l = t - (484 * a - 32 * a * (a - 1));
  int ri, rj, sj;
  if (l < 36) {                      // diagonal super (si == sj == a)
    sj = a;
    ri = 0;
    while (l >= 8 - ri) { l -= 8 - ri; ++ri; }
    rj = ri + l;
  } else {                           // off-diagonal supers, 64 tiles each
    l -= 36;
    sj = a + 1 + (l >> 6);
    const int ll = l & 63;
    ri = ll >> 3; rj = ll & 7;
  }
  const int bi = a * 8 + ri;
  const int bj = sj * 8 + rj;
  const int brow = bi * 128;
  const int bcol = bj * 128;
  const bool diag = (bi == bj);
  const bool pair = (bj - bi == PAIR_OFF);  // contains positive-pair diagonal

  f32x4 acc[4][4];
  const f32x4 zero = {0.f, 0.f, 0.f, 0.f};
  #pragma unroll
  for (int m = 0; m < 4; ++m)
    #pragma unroll
    for (int n = 0; n < 4; ++n) acc[m][n] = zero;

  // stage one BK=128 K-slab (A and B tiles, 16 KB each). 8 global_load_lds
  // per thread (4 A + 4 B). Chunk = 8 rows x 128 B = 1 KB (one wave-load).
  // LDS dest linear; global source pre-swizzled: 16B-slot ^= (row & 7).
  const int srow = (lane >> 3);                  // 0..7 row within chunk
  const int skof = 16 * ((lane & 7) ^ srow);     // pre-swizzled k-offset (bytes)
  auto stage = [&](int k0) {
    #pragma unroll
    for (int i = 0; i < 4; ++i) {
      const int c = w * 4 + i;                   // chunk 0..15 (8 rows each)
      const int row_in = c * 8 + srow;
      const unsigned char* ga = z + (size_t)(brow + row_in) * ZPITCH + k0 + skof;
      const unsigned char* gb = z + (size_t)(bcol + row_in) * ZPITCH + k0 + skof;
      __builtin_amdgcn_global_load_lds(
          (const __attribute__((address_space(1))) void*)ga,
          (__attribute__((address_space(3))) void*)(&As[c * 1024]), 16, 0, 0);
      __builtin_amdgcn_global_load_lds(
          (const __attribute__((address_space(1))) void*)gb,
          (__attribute__((address_space(3))) void*)(&Bs[c * 1024]), 16, 0, 0);
    }
  };

  const int r0 = lane & 15;
  const int g  = lane >> 4;

  for (int kt = 0; kt < 4; ++kt) {
    stage(kt * 128);
    // single buffer: own loads drained, then all waves' loads visible.
    asm volatile("s_waitcnt vmcnt(0)" ::: "memory");
    __builtin_amdgcn_s_barrier();

    const char* Ab = (const char*)&As[0] + (size_t)(wr * 64 + r0) * 128;
    const char* Bb = (const char*)&Bs[0] + (size_t)(wc * 64 + r0) * 128;
    #pragma unroll
    for (int p = 0; p < 2; ++p) {
      // 16-B read at phys slot (2g+p)^(r0&7): R4-verified 0-conflict pattern.
      const int cb = (((2 * g + p) ^ (r0 & 7)) << 4);
      lx2 bfrag[4];
      #pragma unroll
      for (int n = 0; n < 4; ++n)
        bfrag[n] = *(const lx2*)(Bb + n * (16 * 128) + cb);
      #pragma unroll
      for (int m = 0; m < 4; ++m) {
        lx2 afrag = *(const lx2*)(Ab + m * (16 * 128) + cb);
        #pragma unroll
        for (int n = 0; n < 4; ++n) {
          acc[m][n] = __builtin_amdgcn_mfma_f32_16x16x32_fp8_fp8(
              afrag[0], bfrag[n][0], acc[m][n], 0, 0, 0);
          acc[m][n] = __builtin_amdgcn_mfma_f32_16x16x32_fp8_fp8(
              afrag[1], bfrag[n][1], acc[m][n], 0, 0, 0);
        }
      }
    }
    // all LDS reads done in this wave, sync all waves -> safe to overwrite.
    asm volatile("s_waitcnt lgkmcnt(0)" ::: "memory");
    __builtin_amdgcn_sched_barrier(0);
    __builtin_amdgcn_s_barrier();
  }

  // ---- epilogue: unscale; exp(10*g); row + col sums; pair dots ----
  // smem reduction arrays aliased into As (all LDS reads drained above).
  float (*racc)[128] = (float (*)[128])As;        // [2][128]
  float (*cacc)[128] = ((float (*)[128])As) + 2;  // [2][128]

  float cs[4] = {0.f, 0.f, 0.f, 0.f};
  const int grow0 = brow + wr * 64;
  const int gcol0 = bcol + wc * 64;
  const float expc = TEMP_INV * DOT_UNSCALE;
  #pragma unroll
  for (int m = 0; m < 4; ++m) {
    #pragma unroll
    for (int j = 0; j < 4; ++j) {
      const int grow = grow0 + m * 16 + g * 4 + j;
      float v = 0.f;
      #pragma unroll
      for (int n = 0; n < 4; ++n) {
        const int gcol = gcol0 + n * 16 + r0;
        const float rawacc = acc[m][n][j];
        const float e = __expf(rawacc * expc);
        if (grow != gcol) { v += e; cs[n] += e; }   // skip self-similarity
        if (pair && (grow + NPER == gcol)) {        // positive-pair raw dot
          const float raw = rawacc * DOT_UNSCALE;
          s[grow] = raw;                            // dot(z_i, z_{i+NPER})
          s[gcol] = raw;                            // symmetric partner
        }
      }
      v += __shfl_xor(v, 1);
      v += __shfl_xor(v, 2);
      v += __shfl_xor(v, 4);
      v += __shfl_xor(v, 8);
      if (r0 == 0) racc[wc][wr * 64 + m * 16 + g * 4 + j] = v;
    }
  }
  #pragma unroll
  for (int n = 0; n < 4; ++n) {
    float v = cs[n];
    v += __shfl_xor(v, 16);
    v += __shfl_xor(v, 32);
    if (lane < 16) cacc[wr][wc * 64 + n * 16 + lane] = v;
  }
  __syncthreads();
  if (tid < 128) {
    atomicAdd(&rowsum[brow + tid], racc[0][tid] + racc[1][tid]);
  } else if (!diag) {
    const int i = tid - 128;
    atomicAdd(&rowsum[bcol + i], cacc[0][i] + cacc[1][i]);
  }
}

// ---------------------------------------------------------------------------
// Kernel 3: loss = mean_i( log(denom_i) - s_i/T ), 32 blocks + atomicAdd
// (out zeroed in k_normalize; stream order guarantees visibility).
// ---------------------------------------------------------------------------
__global__ __launch_bounds__(256) void k_loss(const float* __restrict__ rowsum,
                                              const float* __restrict__ s,
                                              float* __restrict__ out) {
  __shared__ float red[4];
  const int i = blockIdx.x * 256 + threadIdx.x;
  float v = logf(rowsum[i]) - s[i] * TEMP_INV;
  #pragma unroll
  for (int m = 1; m < 64; m <<= 1) v += __shfl_xor(v, m);
  const int w = threadIdx.x >> 6;
  if ((threadIdx.x & 63) == 0) red[w] = v;
  __syncthreads();
  if (threadIdx.x == 0)
    atomicAdd(out, (red[0] + red[1] + red[2] + red[3]) * (1.0f / (float)NROWS));
}

extern "C" void kernel_launch(void* const* d_in, const int* in_sizes, int n_in,
                              void* d_out, int out_size, void* d_ws, size_t ws_size,
                              hipStream_t stream) {
  const float* v0 = (const float*)d_in[0];
  const float* v1 = (const float*)d_in[1];
  float* out = (float*)d_out;

  unsigned char* z = (unsigned char*)d_ws;                  // 8192 x 576 B
  float* rowsum = (float*)((char*)d_ws + (size_t)NROWS * ZPITCH);
  float* s      = rowsum + NROWS;

  k_normalize<<<NROWS / 4, 256, 0, stream>>>(v0, v1, z, rowsum, out);
  k_gemm_sym<<<NBLK, 256, 0, stream>>>(z, rowsum, s);
  k_loss<<<NROWS / 256, 256, 0, stream>>>(rowsum, s, out);
}